// Round 10
// baseline (220.462 us; speedup 1.0000x reference)
//
#include <hip/hip_runtime.h>
#include <math.h>

// nf1 box-inclusion loss — round 10: R8/R9 experiment, hang-proofed.
// Single NON-cooperative dispatch: byte-table screen + coalesced tile phase A
// + device-scope atomic spin barrier — now with a BOUNDED spin: on timeout
// (co-residency violated), set flag -> out[0] = -12345.0 (loud absmax fail)
// instead of hanging the container. R9's "container failed twice" is
// ambiguous (R1 precedent: flakes happen on safe kernels; but a spin barrier
// can hang hard). This converts deadlock into clean signal.
//
// Experiment (unchanged): dur = 87.2±0.4 for EVERY composition with kernels
// <=~50us. dur ~= fill(43, harness re-poison) + kernels (+~8us/extra
// dispatch). H1 = overhead dominates -> single plain dispatch with ~35-40us
// kernel breaks 87. H2 = fixed floor -> 87 stands, declare next round.
//
// Barrier safety: 100 KB dyn LDS => 1 block/CU; grid=256=#CUs; sole resident
// kernel => all blocks co-resident => spin exits in us. Release =
// __threadfence + atomicExch(slot, MAGIC); acquire = atomicAdd poll +
// __threadfence (G16). Slot re-arm across iterations is benign: inputs are
// identical each iteration, so gbuck/keys are input-deterministic.
//
// Exactness (absmax 0.0 rounds 0-7, identical math):
//  - byte bucket (k=255, width 16, sentinel 255) conservative for ANY data;
//  - bucket mismatch => dim-0 disjoint => loss == 1.0 exactly;
//  - bucket match (~1.2%) => exact fp32 dim-0 key test (same ops as ref);
//  - key pass (~2e-4) => full 25-dim reference math.

#define DIMS 25
#define EMB_BOUND 10000.0f
#define FBLK 1024
#define FTROWS 256
#define TILE_BYTES (FTROWS * 2 * DIMS * 4)   // 51200 B
#define TROWS 128
#define TFLOATS (TROWS * 2 * DIMS)
#define MAGIC 0x1F2E3D4Cu
#define TIMEOUT_FLAG 0xDEADBEEFu
#define MAX_POLLS (1u << 20)

// ---------------- ultimate fallback (exact, no assumptions) ------------------
__global__ void init_ws_kernel(float* ws) {
    if (threadIdx.x == 0 && blockIdx.x == 0) ws[0] = 0.0f;
}

__global__ __launch_bounds__(256, 8) void nf1_fallback_kernel(
    const float* __restrict__ emb, const int2* __restrict__ pairs,
    int n_pairs, float* __restrict__ ws)
{
    const int gl  = threadIdx.x & 31;
    const int gid = blockIdx.x * (blockDim.x >> 5) + (threadIdx.x >> 5);
    const int ngrp = gridDim.x * (blockDim.x >> 5);
    float acc = 0.0f;
    for (int p = gid; p < n_pairs; p += ngrp) {
        int2 pr = pairs[p];
        const float* rc = emb + (size_t)pr.x * (2 * DIMS);
        const float* rd = emb + (size_t)pr.y * (2 * DIMS);
        float t = 1.0f, a = 1.0f;
        if (gl < DIMS) {
            float cc = rc[gl], co = fabsf(rc[DIMS + gl]);
            float dc = rd[gl], dd = fabsf(rd[DIMS + gl]);
            float lo = fmaxf(cc - co, dc - dd);
            float hi = fminf(cc + co, dc + dd);
            t = fmaxf(hi - lo, 0.0f);
            a = 2.0f * co;
        }
        #pragma unroll
        for (int m = 16; m >= 1; m >>= 1) { t *= __shfl_xor(t, m, 32); a *= __shfl_xor(a, m, 32); }
        float loss;
        if (a == 0.0f)     loss = 0.0f;
        else if (isinf(a)) loss = 1.0f - t / (2.0f * EMB_BOUND);
        else               loss = 1.0f - t / a;
        loss = fmaxf(loss, 0.0f);
        if (gl == 0) acc += loss * loss;
    }
    #pragma unroll
    for (int m = 32; m >= 1; m >>= 1) acc += __shfl_xor(acc, m, 64);
    __shared__ float wsum[4];
    if ((threadIdx.x & 63) == 0) wsum[threadIdx.x >> 6] = acc;
    __syncthreads();
    if (threadIdx.x == 0) atomicAdd(ws, wsum[0] + wsum[1] + wsum[2] + wsum[3]);
}

__global__ void fallback_finalize_kernel(const float* __restrict__ ws, float* __restrict__ out) {
    if (threadIdx.x == 0 && blockIdx.x == 0) out[0] = sqrtf(fmaxf(ws[0], 0.0f));
}

// ---------------- shared helpers --------------------------------------------
__device__ __forceinline__ float slow_pair(const float* __restrict__ emb, int2 pr) {
    const float* ra = emb + (size_t)pr.x * (2 * DIMS);
    const float* rb = emb + (size_t)pr.y * (2 * DIMS);
    float inter = 1.0f, carea = 1.0f;
    for (int j = 0; j < DIMS; j++) {
        float cc = ra[j], co = fabsf(ra[DIMS + j]);
        float dc = rb[j], dd = fabsf(rb[DIMS + j]);
        float lo = fmaxf(cc - co, dc - dd);
        float hi = fminf(cc + co, dc + dd);
        inter *= fmaxf(hi - lo, 0.0f);
        carea *= 2.0f * co;
    }
    float loss;
    if (carea == 0.0f)     loss = 0.0f;
    else if (isinf(carea)) loss = 1.0f - inter / (2.0f * EMB_BOUND);
    else                   loss = 1.0f - inter / carea;
    loss = fmaxf(loss, 0.0f);
    return loss * loss;
}

__device__ __forceinline__ float key_pair(const float2* __restrict__ keys,
                                          const float* __restrict__ emb, int2 pr) {
    float2 ka = keys[pr.x];
    float2 kb = keys[pr.y];
    float t0 = fminf(ka.y, kb.y) - fmaxf(ka.x, kb.x);   // exact reference dim-0
    if (t0 > 0.0f) return slow_pair(emb, pr);
    return 1.0f;                                         // loss == 1 exactly
}

template <int K>
__device__ __forceinline__ int ring_bucket(float lo, float hi) {
    float w = hi - lo;
    if (w <= 16.0f && fabsf(lo) <= 1.0e6f) {             // NaN -> sentinel
        int i = (int)floorf(lo * 0.0625f);               // width 16, exact
        int b = i % K; if (b < 0) b += K;
        return b;
    }
    return K;                                            // sentinel: always pass
}

__device__ __forceinline__ bool ring_pass(unsigned a, unsigned b, unsigned K) {
    unsigned dd = (a >= b) ? (a - b) : (b - a);
    return (a == K) | (b == K) | (dd <= 1u) | (dd == K - 1u);
}

// ---------------- fused4b: single plain dispatch, bounded spin barrier -------
__global__ __launch_bounds__(FBLK, 1) void fused4b_kernel(
    const float* __restrict__ emb, float2* __restrict__ keys,
    unsigned char* __restrict__ gbuck, const int2* __restrict__ pairs,
    int n_pairs, int n_rows, float* __restrict__ acc,
    unsigned* __restrict__ ticket, unsigned* __restrict__ slots,
    float* __restrict__ out)
{
    extern __shared__ unsigned char smem[];   // aliased: phase-A tile | sbuck
    __shared__ float wsum[FBLK / 64];
    const int nthreads = gridDim.x * blockDim.x;
    const int t = blockIdx.x * blockDim.x + threadIdx.x;
    if (t == 0) { acc[0] = 0.0f; ticket[0] = 0u; }   // covered by release fence

    // ---- phase A: coalesced tile repack ----
    {
        float* tile = (float*)smem;
        const int n_tiles = (n_rows + FTROWS - 1) / FTROWS;
        for (int tIdx = blockIdx.x; tIdx < n_tiles; tIdx += gridDim.x) {
            const int r0 = tIdx * FTROWS;
            const int rows = min(FTROWS, n_rows - r0);
            const int cnt = rows * (2 * DIMS);
            const int n4 = cnt >> 2;
            {
                const float4* g4 = (const float4*)(emb + (size_t)r0 * (2 * DIMS));
                float4* s4 = (float4*)tile;
                for (int i = threadIdx.x; i < n4; i += blockDim.x) s4[i] = g4[i];
                for (int i = (n4 << 2) + threadIdx.x; i < cnt; i += blockDim.x)
                    tile[i] = emb[(size_t)r0 * (2 * DIMS) + i];
            }
            __syncthreads();
            for (int j = threadIdx.x; j < rows; j += blockDim.x) {
                float c = tile[j * (2 * DIMS)];
                float o = fabsf(tile[j * (2 * DIMS) + DIMS]);
                float lo = c - o, hi = c + o;            // same fp32 ops as ref
                keys[r0 + j] = make_float2(lo, hi);
                gbuck[r0 + j] = (unsigned char)ring_bucket<255>(lo, hi);
            }
            __syncthreads();
        }
    }

    // prefetch first oct's pairs: HBM round-trip overlaps barrier+broadcast
    const int noct = n_pairs >> 3;
    const int4* p4 = (const int4*)pairs;
    int4 qa, qb, qc, qd;
    if (t < noct) {
        qa = p4[4 * t + 0]; qb = p4[4 * t + 1];
        qc = p4[4 * t + 2]; qd = p4[4 * t + 3];
    }

    // ---- bounded device-scope spin barrier (1 block/CU => all resident) ----
    __syncthreads();
    __threadfence();                                     // release phase-A writes
    if (threadIdx.x == 0) atomicExch(&slots[blockIdx.x], MAGIC);
    if (threadIdx.x < gridDim.x) {
        unsigned polls = 0;
        while (atomicAdd(&slots[threadIdx.x], 0u) != MAGIC) {
            __builtin_amdgcn_s_sleep(2);
            if (++polls > MAX_POLLS) {                   // deadlock -> clean fail
                atomicExch(&slots[256], TIMEOUT_FLAG);
                break;
            }
        }
    }
    __syncthreads();
    __threadfence();                                     // acquire

    // ---- phase B: broadcast byte table to LDS, then screen ----
    unsigned char* sbuck = smem;
    {
        const int nb16 = (n_rows + 15) >> 4;
        const uint4* g4 = (const uint4*)gbuck;
        uint4* s4 = (uint4*)sbuck;
        for (int i = threadIdx.x; i < nb16; i += blockDim.x) s4[i] = g4[i];
    }
    __syncthreads();

    float sum = 0.0f;
    for (int q = t; q < noct; q += nthreads) {
        if (q != t) {
            qa = p4[4 * q + 0]; qb = p4[4 * q + 1];
            qc = p4[4 * q + 2]; qd = p4[4 * q + 3];
        }
        int2 pr[8] = { make_int2(qa.x, qa.y), make_int2(qa.z, qa.w),
                       make_int2(qb.x, qb.y), make_int2(qb.z, qb.w),
                       make_int2(qc.x, qc.y), make_int2(qc.z, qc.w),
                       make_int2(qd.x, qd.y), make_int2(qd.z, qd.w) };
        unsigned ba[8], bb[8];
        #pragma unroll
        for (int i = 0; i < 8; i++) { ba[i] = sbuck[pr[i].x]; bb[i] = sbuck[pr[i].y]; }
        #pragma unroll
        for (int i = 0; i < 8; i++) {
            if (ring_pass(ba[i], bb[i], 255u)) sum += key_pair(keys, emb, pr[i]); // ~1.2%
            else                               sum += 1.0f;   // certain-disjoint
        }
    }
    for (int p = (noct << 3) + t; p < n_pairs; p += nthreads) {
        int2 pr = pairs[p];
        unsigned a = sbuck[pr.x], b = sbuck[pr.y];
        if (ring_pass(a, b, 255u)) sum += key_pair(keys, emb, pr);
        else                       sum += 1.0f;
    }

    #pragma unroll
    for (int m = 32; m >= 1; m >>= 1) sum += __shfl_xor(sum, m, 64);
    if ((threadIdx.x & 63) == 0) wsum[threadIdx.x >> 6] = sum;
    __syncthreads();
    if (threadIdx.x == 0) {
        float s = 0.0f;
        #pragma unroll
        for (int w = 0; w < FBLK / 64; w++) s += wsum[w];
        atomicAdd(acc, s);
        __threadfence();
        unsigned tk = atomicAdd(ticket, 1u);
        if (tk == gridDim.x - 1) {
            unsigned bad = atomicAdd(&slots[256], 0u);
            float v = sqrtf(fmaxf(atomicAdd(acc, 0.0f), 0.0f));
            out[0] = (bad == TIMEOUT_FLAG) ? -12345.0f : v;   // loud, not hung
        }
    }
}

// ---------------- two-kernel fallback (proven rounds 4/5) --------------------
__global__ __launch_bounds__(256) void repack_tile_kernel(
    const float* __restrict__ emb, float2* __restrict__ keys,
    unsigned char* __restrict__ gbuck, int n_rows,
    float* __restrict__ acc, unsigned* __restrict__ ticket)
{
    __shared__ float tile[TFLOATS];
    if (blockIdx.x == 0 && threadIdx.x == 0) { acc[0] = 0.0f; ticket[0] = 0u; }
    const int n_tiles = (n_rows + TROWS - 1) / TROWS;
    for (int tIdx = blockIdx.x; tIdx < n_tiles; tIdx += gridDim.x) {
        const int r0 = tIdx * TROWS;
        const int rows = min(TROWS, n_rows - r0);
        const int cnt = rows * (2 * DIMS);
        const int n4 = cnt >> 2;
        {
            const float4* g4 = (const float4*)(emb + (size_t)r0 * (2 * DIMS));
            float4* s4 = (float4*)tile;
            for (int i = threadIdx.x; i < n4; i += blockDim.x) s4[i] = g4[i];
            for (int i = (n4 << 2) + threadIdx.x; i < cnt; i += blockDim.x)
                tile[i] = emb[(size_t)r0 * (2 * DIMS) + i];
        }
        __syncthreads();
        for (int j = threadIdx.x; j < rows; j += blockDim.x) {
            float c = tile[j * (2 * DIMS)];
            float o = fabsf(tile[j * (2 * DIMS) + DIMS]);
            float lo = c - o, hi = c + o;
            keys[r0 + j] = make_float2(lo, hi);
            gbuck[r0 + j] = (unsigned char)ring_bucket<255>(lo, hi);
        }
        __syncthreads();
    }
}

__global__ __launch_bounds__(FBLK, 1) void screen_byte_kernel(
    const float2* __restrict__ keys, const unsigned char* __restrict__ gbuck,
    const float* __restrict__ emb, const int2* __restrict__ pairs,
    int n_pairs, int n_rows, float* __restrict__ acc,
    unsigned* __restrict__ ticket, float* __restrict__ out)
{
    extern __shared__ unsigned char sbuck[];
    __shared__ float wsum[FBLK / 64];
    const int nthreads = gridDim.x * blockDim.x;
    const int t = blockIdx.x * blockDim.x + threadIdx.x;
    const int noct = n_pairs >> 3;
    const int4* p4 = (const int4*)pairs;

    int4 qa, qb, qc, qd;
    if (t < noct) {
        qa = p4[4 * t + 0]; qb = p4[4 * t + 1];
        qc = p4[4 * t + 2]; qd = p4[4 * t + 3];
    }
    {
        const int nb16 = (n_rows + 15) >> 4;
        const uint4* g4 = (const uint4*)gbuck;
        uint4* s4 = (uint4*)sbuck;
        for (int i = threadIdx.x; i < nb16; i += blockDim.x) s4[i] = g4[i];
    }
    __syncthreads();

    float sum = 0.0f;
    for (int q = t; q < noct; q += nthreads) {
        if (q != t) {
            qa = p4[4 * q + 0]; qb = p4[4 * q + 1];
            qc = p4[4 * q + 2]; qd = p4[4 * q + 3];
        }
        int2 pr[8] = { make_int2(qa.x, qa.y), make_int2(qa.z, qa.w),
                       make_int2(qb.x, qb.y), make_int2(qb.z, qb.w),
                       make_int2(qc.x, qc.y), make_int2(qc.z, qc.w),
                       make_int2(qd.x, qd.y), make_int2(qd.z, qd.w) };
        unsigned ba[8], bb[8];
        #pragma unroll
        for (int i = 0; i < 8; i++) { ba[i] = sbuck[pr[i].x]; bb[i] = sbuck[pr[i].y]; }
        #pragma unroll
        for (int i = 0; i < 8; i++) {
            if (ring_pass(ba[i], bb[i], 255u)) sum += key_pair(keys, emb, pr[i]);
            else                               sum += 1.0f;
        }
    }
    for (int p = (noct << 3) + t; p < n_pairs; p += nthreads) {
        int2 pr = pairs[p];
        unsigned a = sbuck[pr.x], b = sbuck[pr.y];
        if (ring_pass(a, b, 255u)) sum += key_pair(keys, emb, pr);
        else                       sum += 1.0f;
    }

    #pragma unroll
    for (int m = 32; m >= 1; m >>= 1) sum += __shfl_xor(sum, m, 64);
    if ((threadIdx.x & 63) == 0) wsum[threadIdx.x >> 6] = sum;
    __syncthreads();
    if (threadIdx.x == 0) {
        float s = 0.0f;
        #pragma unroll
        for (int w = 0; w < FBLK / 64; w++) s += wsum[w];
        atomicAdd(acc, s);
        __threadfence();
        unsigned tk = atomicAdd(ticket, 1u);
        if (tk == gridDim.x - 1)
            out[0] = sqrtf(fmaxf(atomicAdd(acc, 0.0f), 0.0f));
    }
}

extern "C" void kernel_launch(void* const* d_in, const int* in_sizes, int n_in,
                              void* d_out, int out_size, void* d_ws, size_t ws_size,
                              hipStream_t stream) {
    const float* emb  = (const float*)d_in[0];     // (100000, 50) fp32
    const int2*  prs  = (const int2*)d_in[1];      // (2000000, 2) int32
    int n_pairs = in_sizes[1] / 2;
    int n_rows  = in_sizes[0] / (2 * DIMS);

    // ws layout: [0]=acc f32, [1]=ticket u32, bytes 256..1283 = slots[257]
    // (256 barrier slots + timeout flag), keys @1536, gbuck after keys.
    float*    ws     = (float*)d_ws;
    unsigned* ticket = (unsigned*)(ws + 1);
    unsigned* slots  = (unsigned*)((char*)d_ws + 256);
    float2*   keys   = (float2*)((char*)d_ws + 1536);
    unsigned char* gbuck = (unsigned char*)(keys + n_rows);
    float*    out    = (float*)d_out;

    const size_t tabBytes = (size_t)((n_rows + 15) & ~15);      // padded table
    const size_t fusedDyn = tabBytes > (size_t)TILE_BYTES ? tabBytes
                                                          : (size_t)TILE_BYTES;
    const bool ws_ok = (ws_size >= 1536 + (size_t)n_rows * 8 + tabBytes + 64) &&
                       ((n_rows & 1) == 0);
    const bool byte_ok = ws_ok && (fusedDyn + 512 <= 160 * 1024);

    if (byte_ok) {
        // single plain dispatch; 1 block/CU by LDS => all 256 blocks resident
        hipLaunchKernelGGL(fused4b_kernel, dim3(256), dim3(FBLK), fusedDyn, stream,
                           emb, keys, gbuck, prs, n_pairs, n_rows,
                           ws, ticket, slots, out);
    } else if (ws_ok && (tabBytes + 512 <= 160 * 1024)) {
        const int n_tiles = (n_rows + TROWS - 1) / TROWS;
        hipLaunchKernelGGL(repack_tile_kernel, dim3(min(n_tiles, 2048)), dim3(256),
                           0, stream, emb, keys, gbuck, n_rows, ws, ticket);
        hipLaunchKernelGGL(screen_byte_kernel, dim3(256), dim3(FBLK),
                           tabBytes, stream,
                           keys, gbuck, emb, prs, n_pairs, n_rows, ws, ticket, out);
    } else {
        hipLaunchKernelGGL(init_ws_kernel, dim3(1), dim3(64), 0, stream, ws);
        hipLaunchKernelGGL(nf1_fallback_kernel, dim3(4096), dim3(256), 0, stream,
                           emb, prs, n_pairs, ws);
        hipLaunchKernelGGL(fallback_finalize_kernel, dim3(1), dim3(64), 0, stream, ws, out);
    }
}

// Round 11
// 87.670 us; speedup vs baseline: 2.5147x; 2.5147x over previous
//
#include <hip/hip_runtime.h>
#include <hip/hip_cooperative_groups.h>
#include <math.h>

namespace cg = cooperative_groups;

// nf1 box-inclusion loss — round 11: restore best-measured kernel (R3 fused2,
// 86.92 us) after the R10 spin-barrier probe (220 us) completed the timing
// model.
//
// FLOOR MODEL (fits all 11 benches within ~1 us):
//   dur ~= fill(43) + max(43, K),  K = kernel time + dispatch overhead.
// The timed window carries ~86 us of harness ws-poison fill (2 x 43 us,
// 268 MB each at ~6.2 TB/s); kernels with K <= 43 hide under the second
// fill. Evidence: R2(K=99)->142, R3(44)->87, R4/5(~44)->87.6/87.1,
// R7(51)->94, R10(177)->220. Current K ~= 44 => dur floor 86-87 REACHED.
// Expected remaining headroom: <= ~1 us. If this round confirms 87 +- 1,
// the session declares the harness-structural floor.
//
// Kernel: single cooperative dispatch; phase A computes keys (lo0,hi0) +
// byte buckets with grid-strided scalar reads (2 floats/row); grid.sync;
// phase B broadcasts the 100 KB byte table to LDS and screens 8 pairs/thread.
//
// Exactness (absmax 0.0 on this exact source, round 3; and rounds 0-7/10
// with identical math):
//  - byte bucket (k=255, width 16, sentinel 255) conservative for ANY data;
//  - bucket mismatch => dim-0 disjoint => loss == 1.0 exactly;
//  - bucket match (~1.2%) => exact fp32 dim-0 key test (same ops as ref);
//  - key pass (~2e-4) => full 25-dim reference math.

#define DIMS 25
#define EMB_BOUND 10000.0f
#define FBLK 1024

// ---------------- ultimate fallback (exact, no assumptions) ------------------
__global__ void init_ws_kernel(float* ws) {
    if (threadIdx.x == 0 && blockIdx.x == 0) ws[0] = 0.0f;
}

__global__ __launch_bounds__(256, 8) void nf1_fallback_kernel(
    const float* __restrict__ emb, const int2* __restrict__ pairs,
    int n_pairs, float* __restrict__ ws)
{
    const int gl  = threadIdx.x & 31;
    const int gid = blockIdx.x * (blockDim.x >> 5) + (threadIdx.x >> 5);
    const int ngrp = gridDim.x * (blockDim.x >> 5);
    float acc = 0.0f;
    for (int p = gid; p < n_pairs; p += ngrp) {
        int2 pr = pairs[p];
        const float* rc = emb + (size_t)pr.x * (2 * DIMS);
        const float* rd = emb + (size_t)pr.y * (2 * DIMS);
        float t = 1.0f, a = 1.0f;
        if (gl < DIMS) {
            float cc = rc[gl], co = fabsf(rc[DIMS + gl]);
            float dc = rd[gl], dd = fabsf(rd[DIMS + gl]);
            float lo = fmaxf(cc - co, dc - dd);
            float hi = fminf(cc + co, dc + dd);
            t = fmaxf(hi - lo, 0.0f);
            a = 2.0f * co;
        }
        #pragma unroll
        for (int m = 16; m >= 1; m >>= 1) { t *= __shfl_xor(t, m, 32); a *= __shfl_xor(a, m, 32); }
        float loss;
        if (a == 0.0f)     loss = 0.0f;
        else if (isinf(a)) loss = 1.0f - t / (2.0f * EMB_BOUND);
        else               loss = 1.0f - t / a;
        loss = fmaxf(loss, 0.0f);
        if (gl == 0) acc += loss * loss;
    }
    #pragma unroll
    for (int m = 32; m >= 1; m >>= 1) acc += __shfl_xor(acc, m, 64);
    __shared__ float wsum[4];
    if ((threadIdx.x & 63) == 0) wsum[threadIdx.x >> 6] = acc;
    __syncthreads();
    if (threadIdx.x == 0) atomicAdd(ws, wsum[0] + wsum[1] + wsum[2] + wsum[3]);
}

__global__ void fallback_finalize_kernel(const float* __restrict__ ws, float* __restrict__ out) {
    if (threadIdx.x == 0 && blockIdx.x == 0) out[0] = sqrtf(fmaxf(ws[0], 0.0f));
}

// ---------------- shared helpers --------------------------------------------
__device__ __forceinline__ float slow_pair(const float* __restrict__ emb, int2 pr) {
    const float* ra = emb + (size_t)pr.x * (2 * DIMS);
    const float* rb = emb + (size_t)pr.y * (2 * DIMS);
    float inter = 1.0f, carea = 1.0f;
    for (int j = 0; j < DIMS; j++) {
        float cc = ra[j], co = fabsf(ra[DIMS + j]);
        float dc = rb[j], dd = fabsf(rb[DIMS + j]);
        float lo = fmaxf(cc - co, dc - dd);
        float hi = fminf(cc + co, dc + dd);
        inter *= fmaxf(hi - lo, 0.0f);
        carea *= 2.0f * co;
    }
    float loss;
    if (carea == 0.0f)     loss = 0.0f;
    else if (isinf(carea)) loss = 1.0f - inter / (2.0f * EMB_BOUND);
    else                   loss = 1.0f - inter / carea;
    loss = fmaxf(loss, 0.0f);
    return loss * loss;
}

__device__ __forceinline__ float key_pair(const float2* __restrict__ keys,
                                          const float* __restrict__ emb, int2 pr) {
    float2 ka = keys[pr.x];
    float2 kb = keys[pr.y];
    float t0 = fminf(ka.y, kb.y) - fmaxf(ka.x, kb.x);   // exact reference dim-0
    if (t0 > 0.0f) return slow_pair(emb, pr);
    return 1.0f;                                         // loss == 1 exactly
}

template <int K>
__device__ __forceinline__ int ring_bucket(float lo, float hi) {
    float w = hi - lo;
    if (w <= 16.0f && fabsf(lo) <= 1.0e6f) {             // NaN -> sentinel
        int i = (int)floorf(lo * 0.0625f);               // width 16, exact
        int b = i % K; if (b < 0) b += K;
        return b;
    }
    return K;                                            // sentinel: always pass
}

__device__ __forceinline__ bool ring_pass(unsigned a, unsigned b, unsigned K) {
    unsigned dd = (a >= b) ? (a - b) : (b - a);
    return (a == K) | (b == K) | (dd <= 1u) | (dd == K - 1u);
}

// grid-stride LDS-byte screen over all pairs; returns per-thread sum
__device__ __forceinline__ float screen_pairs(
    const unsigned char* __restrict__ sbuck, const float2* __restrict__ keys,
    const float* __restrict__ emb, const int2* __restrict__ pairs,
    int n_pairs, int t, int nthreads)
{
    float sum = 0.0f;
    const int noct = n_pairs >> 3;                       // 8 pairs per iteration
    const int4* p4 = (const int4*)pairs;
    for (int q = t; q < noct; q += nthreads) {
        int4 qa = p4[4 * q + 0], qb = p4[4 * q + 1];
        int4 qc = p4[4 * q + 2], qd = p4[4 * q + 3];
        int2 pr[8] = { make_int2(qa.x, qa.y), make_int2(qa.z, qa.w),
                       make_int2(qb.x, qb.y), make_int2(qb.z, qb.w),
                       make_int2(qc.x, qc.y), make_int2(qc.z, qc.w),
                       make_int2(qd.x, qd.y), make_int2(qd.z, qd.w) };
        unsigned ba[8], bb[8];
        #pragma unroll
        for (int i = 0; i < 8; i++) { ba[i] = sbuck[pr[i].x]; bb[i] = sbuck[pr[i].y]; }
        #pragma unroll
        for (int i = 0; i < 8; i++) {
            if (ring_pass(ba[i], bb[i], 255u)) sum += key_pair(keys, emb, pr[i]); // ~1.2%
            else                               sum += 1.0f;   // certain-disjoint
        }
    }
    for (int p = (noct << 3) + t; p < n_pairs; p += nthreads) {
        int2 pr = pairs[p];
        unsigned a = sbuck[pr.x], b = sbuck[pr.y];
        if (ring_pass(a, b, 255u)) sum += key_pair(keys, emb, pr);
        else                       sum += 1.0f;
    }
    return sum;
}

// ---------------- fused cooperative kernel (preferred) -----------------------
__global__ __launch_bounds__(FBLK, 1) void fused2_kernel(
    const float* __restrict__ emb, float2* __restrict__ keys,
    unsigned char* __restrict__ gbuck, const int2* __restrict__ pairs,
    int n_pairs, int n_rows, float* __restrict__ acc,
    unsigned* __restrict__ ticket, float* __restrict__ out)
{
    extern __shared__ unsigned char sbuck[];             // 100 KB byte table
    __shared__ float wsum[FBLK / 64];
    const int nthreads = gridDim.x * blockDim.x;
    const int t = blockIdx.x * blockDim.x + threadIdx.x;
    if (t == 0) { acc[0] = 0.0f; ticket[0] = 0u; }

    // phase A: keys + buckets (2 scalar reads/row, grid-strided)
    for (int r = t; r < n_rows; r += nthreads) {
        float c = emb[(size_t)r * (2 * DIMS)];
        float o = fabsf(emb[(size_t)r * (2 * DIMS) + DIMS]);
        float lo = c - o, hi = c + o;                    // same fp32 ops as ref
        keys[r] = make_float2(lo, hi);
        gbuck[r] = (unsigned char)ring_bucket<255>(lo, hi);
    }

    cg::this_grid().sync();

    // phase B: broadcast table to LDS (coalesced uint4), then screen
    {
        const int nb16 = (n_rows + 15) >> 4;
        const uint4* g4 = (const uint4*)gbuck;
        uint4* s4 = (uint4*)sbuck;
        for (int i = threadIdx.x; i < nb16; i += blockDim.x) s4[i] = g4[i];
    }
    __syncthreads();

    float sum = screen_pairs(sbuck, keys, emb, pairs, n_pairs, t, nthreads);

    #pragma unroll
    for (int m = 32; m >= 1; m >>= 1) sum += __shfl_xor(sum, m, 64);
    if ((threadIdx.x & 63) == 0) wsum[threadIdx.x >> 6] = sum;
    __syncthreads();
    if (threadIdx.x == 0) {
        float s = 0.0f;
        #pragma unroll
        for (int w = 0; w < FBLK / 64; w++) s += wsum[w];
        atomicAdd(acc, s);
        __threadfence();
        unsigned tk = atomicAdd(ticket, 1u);
        if (tk == gridDim.x - 1)
            out[0] = sqrtf(fmaxf(atomicAdd(acc, 0.0f), 0.0f));
    }
}

// ---------------- two-kernel fallback (non-coop) -----------------------------
__global__ __launch_bounds__(256) void repack_kb_kernel(
    const float* __restrict__ emb, float2* __restrict__ keys,
    unsigned char* __restrict__ gbuck, int n_rows,
    float* __restrict__ acc, unsigned* __restrict__ ticket)
{
    if (blockIdx.x == 0 && threadIdx.x == 0) { acc[0] = 0.0f; ticket[0] = 0u; }
    const int r = blockIdx.x * blockDim.x + threadIdx.x;
    if (r < n_rows) {
        float c = emb[(size_t)r * (2 * DIMS)];
        float o = fabsf(emb[(size_t)r * (2 * DIMS) + DIMS]);
        float lo = c - o, hi = c + o;
        keys[r] = make_float2(lo, hi);
        gbuck[r] = (unsigned char)ring_bucket<255>(lo, hi);
    }
}

__global__ __launch_bounds__(FBLK, 1) void screen_byte2_kernel(
    const float2* __restrict__ keys, const unsigned char* __restrict__ gbuck,
    const float* __restrict__ emb, const int2* __restrict__ pairs,
    int n_pairs, int n_rows, float* __restrict__ acc,
    unsigned* __restrict__ ticket, float* __restrict__ out)
{
    extern __shared__ unsigned char sbuck[];
    __shared__ float wsum[FBLK / 64];
    const int nthreads = gridDim.x * blockDim.x;
    const int t = blockIdx.x * blockDim.x + threadIdx.x;
    {
        const int nb16 = (n_rows + 15) >> 4;
        const uint4* g4 = (const uint4*)gbuck;
        uint4* s4 = (uint4*)sbuck;
        for (int i = threadIdx.x; i < nb16; i += blockDim.x) s4[i] = g4[i];
    }
    __syncthreads();

    float sum = screen_pairs(sbuck, keys, emb, pairs, n_pairs, t, nthreads);

    #pragma unroll
    for (int m = 32; m >= 1; m >>= 1) sum += __shfl_xor(sum, m, 64);
    if ((threadIdx.x & 63) == 0) wsum[threadIdx.x >> 6] = sum;
    __syncthreads();
    if (threadIdx.x == 0) {
        float s = 0.0f;
        #pragma unroll
        for (int w = 0; w < FBLK / 64; w++) s += wsum[w];
        atomicAdd(acc, s);
        __threadfence();
        unsigned tk = atomicAdd(ticket, 1u);
        if (tk == gridDim.x - 1)
            out[0] = sqrtf(fmaxf(atomicAdd(acc, 0.0f), 0.0f));
    }
}

extern "C" void kernel_launch(void* const* d_in, const int* in_sizes, int n_in,
                              void* d_out, int out_size, void* d_ws, size_t ws_size,
                              hipStream_t stream) {
    const float* emb  = (const float*)d_in[0];     // (100000, 50) fp32
    const int2*  prs  = (const int2*)d_in[1];      // (2000000, 2) int32
    int n_pairs = in_sizes[1] / 2;
    int n_rows  = in_sizes[0] / (2 * DIMS);

    float*    ws     = (float*)d_ws;                // ws[0]=acc, ws[1]=ticket
    unsigned* ticket = (unsigned*)(ws + 1);
    float*    out    = (float*)d_out;
    float2*   keys   = (float2*)((char*)d_ws + 256);            // 8B * n_rows
    unsigned char* gbuck = (unsigned char*)(keys + n_rows);     // byte table
    // gbuck byte offset = 256 + 8*n_rows: 16B-aligned for even n_rows.

    int dev = 0;  hipGetDevice(&dev);
    int maxShared = 0, coop = 0, numCU = 0;
    hipDeviceGetAttribute(&maxShared, hipDeviceAttributeMaxSharedMemoryPerBlock, dev);
    hipDeviceGetAttribute(&coop, hipDeviceAttributeCooperativeLaunch, dev);
    hipDeviceGetAttribute(&numCU, hipDeviceAttributeMultiprocessorCount, dev);

    const size_t tabBytes = (size_t)((n_rows + 15) & ~15);      // padded table
    const bool ws_ok = (ws_size >= 256 + (size_t)n_rows * 8 + tabBytes + 64) &&
                       ((n_rows & 1) == 0);
    const bool byte_ok = ((size_t)maxShared >= tabBytes + 512) && ws_ok;

    bool launched = false;
    if (byte_ok && coop && numCU > 0) {
        int blocksPerCU = 0;
        hipError_t oe = hipOccupancyMaxActiveBlocksPerMultiprocessor(
            &blocksPerCU, (const void*)fused2_kernel, FBLK, tabBytes);
        if (oe == hipSuccess && blocksPerCU >= 1) {
            int grid = blocksPerCU * numCU;               // all co-resident
            void* args[] = { (void*)&emb, (void*)&keys, (void*)&gbuck,
                             (void*)&prs, (void*)&n_pairs, (void*)&n_rows,
                             (void*)&ws, (void*)&ticket, (void*)&out };
            hipError_t le = hipLaunchCooperativeKernel(
                (const void*)fused2_kernel, dim3(grid), dim3(FBLK),
                args, (unsigned int)tabBytes, stream);
            if (le == hipSuccess) launched = true;
        }
    }

    if (!launched && byte_ok) {
        const int rblocks = (n_rows + 255) / 256;
        hipLaunchKernelGGL(repack_kb_kernel, dim3(rblocks), dim3(256), 0, stream,
                           emb, keys, gbuck, n_rows, ws, ticket);
        const int grid = (numCU > 0) ? numCU : 256;
        hipLaunchKernelGGL(screen_byte2_kernel, dim3(grid), dim3(FBLK),
                           tabBytes, stream,
                           keys, gbuck, emb, prs, n_pairs, n_rows, ws, ticket, out);
        launched = true;
    }

    if (!launched) {
        hipLaunchKernelGGL(init_ws_kernel, dim3(1), dim3(64), 0, stream, ws);
        hipLaunchKernelGGL(nf1_fallback_kernel, dim3(4096), dim3(256), 0, stream,
                           emb, prs, n_pairs, ws);
        hipLaunchKernelGGL(fallback_finalize_kernel, dim3(1), dim3(64), 0, stream, ws, out);
    }
}